// Round 7
// baseline (139.793 us; speedup 1.0000x reference)
//
#include <hip/hip_runtime.h>

// Problem constants
static constexpr int NB   = 128;   // batch
static constexpr int NCIN = 64;    // input channels
static constexpr int NG   = 8;     // groups
static constexpr int NH   = 14;    // spatial
static constexpr int NP   = 16;    // mixed width
static constexpr int HH   = NH * NH;       // 196
static constexpr int LROW = 20;    // padded t4s row (l in [-2,17])

// LDS layout (float offsets). NO x staging buffer anymore: phase B reads x
// directly from global (reg double-buffered). Peak LDS = 4352 floats.
static constexpr int OFF_T4 = 0;      // [8][16][20] = 2560
static constexpr int OFF_W2 = 2560;   // [8][5][32]  = 1280
static constexpr int OFF_WC = 3840;   // [2][8][32]  =  512
static constexpr int LDS_FLOATS = 4352;   // 17,408 B -> 8 blocks/CU (wave-capped)
// out staging (256 ch x 15) reuses lds[0 .. 3840) after conv, two rounds

// FMA quarter: 16 j-values from reg buffer `buf`, wmix rows qb..qb+15 via s_load
#define FMAQ(buf, qb)                                                          \
    do {                                                                       \
        _Pragma("unroll")                                                      \
        for (int j4 = 0; j4 < 4; j4++) {                                       \
            _Pragma("unroll")                                                  \
            for (int pp = 0; pp < 8; pp++) {                                   \
                const int p_ = p0 + pp; /* wave-uniform -> s_load */           \
                am[pp] += buf[j4 * 4 + 0] * wmix[((qb) + j4 * 4 + 0) * NP + p_]\
                        + buf[j4 * 4 + 1] * wmix[((qb) + j4 * 4 + 1) * NP + p_]\
                        + buf[j4 * 4 + 2] * wmix[((qb) + j4 * 4 + 2) * NP + p_]\
                        + buf[j4 * 4 + 3] * wmix[((qb) + j4 * 4 + 3) * NP + p_];\
            }                                                                  \
        }                                                                      \
    } while (0)

// ---------------------------------------------------------------------------
// Fully fused kernel. block = (b, o), 256 threads, 8 blocks/CU resident.
//   - phase B (mix): each active thread owns one gl = g*14+l and a wave-
//     uniform p-half; loads its 64 x[j] DIRECTLY from global in 4 reg-
//     double-buffered quarters (no LDS, no barriers). Duplicate p-half wave
//     hits L1/L2. wmix via s_load (wave-uniform).
//   - w2s/wcs diag-sums written from regs BEFORE phase B (region free now).
//   - conv: verified 5-tap structure, unchanged.
//   - output: verified mod-14 rotation staging, in two 256-channel rounds
//     (keeps LDS peak at 4352 floats); float2 global stores.
//   Barriers: 5 (was 7). LDS 30.7 KB -> 17.4 KB.
// ---------------------------------------------------------------------------
__global__ __launch_bounds__(256, 8) void fused_kernel(const float* __restrict__ x,
                                                       const float* __restrict__ wconv,
                                                       const float* __restrict__ wmix,
                                                       float* __restrict__ out) {
    __shared__ __align__(16) float lds[LDS_FLOATS];
    float* t4s = lds + OFF_T4;
    float* w2s = lds + OFF_W2;
    float* wcs = lds + OFF_WC;

    const int tid   = threadIdx.x;
    const int b     = blockIdx.x / NH;
    const int o     = blockIdx.x % NH;
    const int o_src = (o + NH - 1) % NH;

    // ---- wconv loads (9 per thread, coalesced); consumed before phase B ----
    const int gW = tid >> 5, jW = tid & 31;
    float wv9[9];
    {
        const float* wp = wconv + (size_t)(gW * 9) * 32 + jW;
#pragma unroll
        for (int t = 0; t < 9; t++) wv9[t] = wp[t * 32];
    }

    // ---- phase-B geometry: thread = (gl, p-half) ----
    const int  lane128 = tid & 127;
    const bool xact    = lane128 < 112;
    const int  gS      = lane128 / 14;
    const int  lS      = lane128 % 14;
    const int  p0      = __builtin_amdgcn_readfirstlane((tid >> 7) << 3);  // 0/8
    const float* xg    = x + (size_t)b * (NCIN * NG * HH) + (size_t)gS * HH
                           + o_src * NH + lS;

    // issue x quarter 0 (j = 0..15) while w2s/pads execute
    float xq0[16], xq1[16];
    if (xact) {
#pragma unroll
        for (int r = 0; r < 16; r++) xq0[r] = xg[(size_t)r * (NG * HH)];
    }

    // ---- W2 diag-sums + corrections from regs (xs region is free now) ----
    {
        float d0 = wv9[0];
        float d1 = wv9[1] + wv9[3];
        float d2 = wv9[2] + wv9[4] + wv9[6];
        float d3 = wv9[5] + wv9[7];
        float d4 = wv9[8];
        float* wp2 = w2s + gW * 160 + jW;
        wp2[0]   = d0;
        wp2[32]  = d1;
        wp2[64]  = d2;
        wp2[96]  = d3;
        wp2[128] = d4;
        wcs[gW * 32 + jW]       = wv9[2];        // w[0][2]
        wcs[256 + gW * 32 + jW] = wv9[6];        // w[2][0]
    }
    // ---- zero t4s pad columns l2 in {0,1,16,17,18,19} ----
#pragma unroll
    for (int r = 0; r < 3; r++) {                // 768 entries
        int idx = r * 256 + tid;
        int gp  = idx / 6;
        int s   = idx % 6;
        int l2  = (s < 2) ? s : (14 + s);
        t4s[gp * LROW + l2] = 0.f;
    }

    // ---- phase B: direct-global mix, reg-double-buffered j-quarters ----
    float am[8] = {0.f, 0.f, 0.f, 0.f, 0.f, 0.f, 0.f, 0.f};
    if (xact) {
#pragma unroll
        for (int r = 0; r < 16; r++) xq1[r] = xg[(size_t)(16 + r) * (NG * HH)];
        FMAQ(xq0, 0);
#pragma unroll
        for (int r = 0; r < 16; r++) xq0[r] = xg[(size_t)(32 + r) * (NG * HH)];
        FMAQ(xq1, 16);
#pragma unroll
        for (int r = 0; r < 16; r++) xq1[r] = xg[(size_t)(48 + r) * (NG * HH)];
        FMAQ(xq0, 32);
        FMAQ(xq1, 48);
        // scatter t4 slice into conv layout t4s[(g*16+p)*20 + l+2]
#pragma unroll
        for (int pp = 0; pp < 8; pp++) {
            t4s[(gS * 16 + p0 + pp) * LROW + lS + 2] = am[pp];
        }
    }
    __syncthreads();   // barrier 1: t4s/w2s/wcs ready

    // ================= conv phase (verified structure, unchanged) ==========
    const int p  = tid & 15;
    const int jh = tid >> 4;        // 0..15
    const int jb = jh * 2;          // channels j = jb, jb+1

    float acc[NH][2];
#pragma unroll
    for (int n = 0; n < NH; n++) { acc[n][0] = 0.f; acc[n][1] = 0.f; }

    for (int g = 0; g < NG; g++) {
        float row[LROW];
        const float* rp = &t4s[(g * 16 + p) * LROW];
#pragma unroll
        for (int q = 0; q < 5; q++) {
            float4 v = *reinterpret_cast<const float4*>(rp + q * 4);
            row[q * 4 + 0] = v.x; row[q * 4 + 1] = v.y;
            row[q * 4 + 2] = v.z; row[q * 4 + 3] = v.w;
        }
#pragma unroll
        for (int di = 0; di < 5; di++) {
            float2 w = *reinterpret_cast<const float2*>(&w2s[(g * 5 + di) * 32 + jb]);
#pragma unroll
            for (int n = 0; n < NH; n++) {
                float rv = row[n + di];
                acc[n][0] += rv * w.x;
                acc[n][1] += rv * w.y;
            }
        }
        float2 c0 = *reinterpret_cast<const float2*>(&wcs[g * 32 + jb]);
        float2 c1 = *reinterpret_cast<const float2*>(&wcs[256 + g * 32 + jb]);
        float r2 = row[2], r15 = row[15];
        acc[0][0]  -= r2  * c0.x; acc[0][1]  -= r2  * c0.y;
        acc[13][0] -= r15 * c1.x; acc[13][1] -= r15 * c1.y;
    }

    __syncthreads();   // barrier 2: conv reads done; reuse lds[0,3840) as stage

    // ---- output in two 256-channel rounds; verified mod-14 rotation,
    //      stride 15 (injective, slot 14 unused), float2 global stores ----
    // this thread's owned channels: c = jh*32 + jj*16 + p  ->  c>>5 == jh
    int rotw = jh * 2;
    rotw -= (rotw >= 14) ? 14 : 0;
    rotw -= (rotw >= 14) ? 14 : 0;               // 2*jh <= 30: two wraps max

    const int k7 = tid & 7;
    const int cb = tid >> 3;                     // 0..31
    float* ob = out + (size_t)b * 512 * HH + (size_t)o * NH;

#pragma unroll
    for (int h = 0; h < 2; h++) {
        if ((jh >> 3) == h) {                    // owners of half h stage
#pragma unroll
            for (int jj = 0; jj < 2; jj++) {
                int cl = ((jb + jj) * 16 + p) & 255;   // local channel 0..255
                int sb = cl * 15;
#pragma unroll
                for (int n = 0; n < NH; n++) {
                    int rn = n + rotw;
                    rn -= (rn >= 14) ? 14 : 0;
                    lds[sb + rn] = acc[n][jj];
                }
            }
        }
        __syncthreads();                         // staged
        if (k7 < 7) {
#pragma unroll
            for (int r = 0; r < 8; r++) {        // 256 channels = 32 cb x 8 r
                int cl  = cb + 32 * r;
                int cg  = h * 256 + cl;          // c>>5 = h*8 + r
                int rot = (2 * (h * 8 + r)) % 14;   // compile-time per (h,r)
                int rn  = 2 * k7 + rot;          // even, <= 24
                rn -= (rn >= 14) ? 14 : 0;       // even, <= 12 -> rn+1 safe
                float v0 = lds[cl * 15 + rn];
                float v1 = lds[cl * 15 + rn + 1];
                *reinterpret_cast<float2*>(ob + (size_t)cg * HH + 2 * k7) =
                    make_float2(v0, v1);
            }
        }
        __syncthreads();                         // reads done before next stage
    }
}

extern "C" void kernel_launch(void* const* d_in, const int* in_sizes, int n_in,
                              void* d_out, int out_size, void* d_ws, size_t ws_size,
                              hipStream_t stream) {
    const float* x     = (const float*)d_in[0];
    const float* wconv = (const float*)d_in[1];
    const float* wmix  = (const float*)d_in[2];
    float* out = (float*)d_out;
    (void)d_ws; (void)ws_size;

    // one block per (b, o)
    fused_kernel<<<NB * NH, 256, 0, stream>>>(x, wconv, wmix, out);
}

// Round 8
// 133.805 us; speedup vs baseline: 1.0448x; 1.0448x over previous
//
#include <hip/hip_runtime.h>

// Problem constants
static constexpr int NB   = 128;   // batch
static constexpr int NCIN = 64;    // input channels
static constexpr int NG   = 8;     // groups
static constexpr int NH   = 14;    // spatial
static constexpr int NP   = 16;    // mixed width
static constexpr int HH   = NH * NH;       // 196
static constexpr int LROW = 20;    // padded t4s row (l in [-2,17])

// LDS layout (float offsets). Phase B reads x directly from global.
static constexpr int OFF_T4 = 0;      // [8][16][20] = 2560
static constexpr int OFF_W2 = 2560;   // [8][5][32]  = 1280
static constexpr int OFF_WC = 3840;   // [2][8][32]  =  512
static constexpr int LDS_FLOATS = 4352;   // 17,408 B -> 8 blocks/CU (wave-capped)
// out staging (256 ch x 15) reuses lds[0 .. 3840) after conv, two rounds

// FMA quarter: 16 j-values from reg buffer `buf`, wmix rows qb..qb+15 via s_load
#define FMAQ(buf, qb)                                                          \
    do {                                                                       \
        _Pragma("unroll")                                                      \
        for (int j4 = 0; j4 < 4; j4++) {                                       \
            _Pragma("unroll")                                                  \
            for (int pp = 0; pp < 8; pp++) {                                   \
                const int p_ = p0 + pp; /* wave-uniform -> s_load */           \
                am[pp] += buf[j4 * 4 + 0] * wmix[((qb) + j4 * 4 + 0) * NP + p_]\
                        + buf[j4 * 4 + 1] * wmix[((qb) + j4 * 4 + 1) * NP + p_]\
                        + buf[j4 * 4 + 2] * wmix[((qb) + j4 * 4 + 2) * NP + p_]\
                        + buf[j4 * 4 + 3] * wmix[((qb) + j4 * 4 + 3) * NP + p_];\
            }                                                                  \
        }                                                                      \
    } while (0)

// ---------------------------------------------------------------------------
// Fully fused kernel. block = (b, o), 256 threads, 8 blocks/CU resident.
//   R8 change (ONLY change vs verified R7): XCD-aware bid->(b,o) swizzle.
//   Out row (b,c) = 784 B is written in 56 B pieces by the 14 o-blocks of b.
//   With bid = b*14+o and round-robin XCD = bid%8, those 14 writers sit on
//   DIFFERENT non-coherent L2s -> partial-line writebacks + write-allocate
//   fetches (measured: WRITE 95.5 MB vs 51.4 ideal, FETCH +RMW). Remap
//     xcd = bid&7; t = bid>>3; o = t%14; b = xcd + 8*(t/14)
//   so all 14 o-blocks of a batch share one XCD/L2 -> lines merge fully.
//   - phase B (mix): thread owns one gl + wave-uniform p-half; 64 x[j] loads
//     direct from global, reg-double-buffered; wmix via s_load. No barriers.
//   - conv: verified 5-tap structure, unchanged.
//   - output: verified mod-14 rotation staging, two 256-channel rounds.
// ---------------------------------------------------------------------------
__global__ __launch_bounds__(256, 8) void fused_kernel(const float* __restrict__ x,
                                                       const float* __restrict__ wconv,
                                                       const float* __restrict__ wmix,
                                                       float* __restrict__ out) {
    __shared__ __align__(16) float lds[LDS_FLOATS];
    float* t4s = lds + OFF_T4;
    float* w2s = lds + OFF_W2;
    float* wcs = lds + OFF_WC;

    const int tid = threadIdx.x;
    // ---- XCD-aware decode: all 14 o-blocks of a given b share bid%8 ----
    const int bid = blockIdx.x;                  // 0..1791
    const int xcd = bid & 7;
    const int t8  = bid >> 3;                    // 0..223
    const int o   = t8 % NH;
    const int b   = xcd + 8 * (t8 / NH);
    const int o_src = (o + NH - 1) % NH;

    // ---- wconv loads (9 per thread, coalesced); consumed before phase B ----
    const int gW = tid >> 5, jW = tid & 31;
    float wv9[9];
    {
        const float* wp = wconv + (size_t)(gW * 9) * 32 + jW;
#pragma unroll
        for (int t = 0; t < 9; t++) wv9[t] = wp[t * 32];
    }

    // ---- phase-B geometry: thread = (gl, p-half) ----
    const int  lane128 = tid & 127;
    const bool xact    = lane128 < 112;
    const int  gS      = lane128 / 14;
    const int  lS      = lane128 % 14;
    const int  p0      = __builtin_amdgcn_readfirstlane((tid >> 7) << 3);  // 0/8
    const float* xg    = x + (size_t)b * (NCIN * NG * HH) + (size_t)gS * HH
                           + o_src * NH + lS;

    // issue x quarter 0 (j = 0..15) while w2s/pads execute
    float xq0[16], xq1[16];
    if (xact) {
#pragma unroll
        for (int r = 0; r < 16; r++) xq0[r] = xg[(size_t)r * (NG * HH)];
    }

    // ---- W2 diag-sums + corrections from regs ----
    {
        float d0 = wv9[0];
        float d1 = wv9[1] + wv9[3];
        float d2 = wv9[2] + wv9[4] + wv9[6];
        float d3 = wv9[5] + wv9[7];
        float d4 = wv9[8];
        float* wp2 = w2s + gW * 160 + jW;
        wp2[0]   = d0;
        wp2[32]  = d1;
        wp2[64]  = d2;
        wp2[96]  = d3;
        wp2[128] = d4;
        wcs[gW * 32 + jW]       = wv9[2];        // w[0][2]
        wcs[256 + gW * 32 + jW] = wv9[6];        // w[2][0]
    }
    // ---- zero t4s pad columns l2 in {0,1,16,17,18,19} ----
#pragma unroll
    for (int r = 0; r < 3; r++) {                // 768 entries
        int idx = r * 256 + tid;
        int gp  = idx / 6;
        int s   = idx % 6;
        int l2  = (s < 2) ? s : (14 + s);
        t4s[gp * LROW + l2] = 0.f;
    }

    // ---- phase B: direct-global mix, reg-double-buffered j-quarters ----
    float am[8] = {0.f, 0.f, 0.f, 0.f, 0.f, 0.f, 0.f, 0.f};
    if (xact) {
#pragma unroll
        for (int r = 0; r < 16; r++) xq1[r] = xg[(size_t)(16 + r) * (NG * HH)];
        FMAQ(xq0, 0);
#pragma unroll
        for (int r = 0; r < 16; r++) xq0[r] = xg[(size_t)(32 + r) * (NG * HH)];
        FMAQ(xq1, 16);
#pragma unroll
        for (int r = 0; r < 16; r++) xq1[r] = xg[(size_t)(48 + r) * (NG * HH)];
        FMAQ(xq0, 32);
        FMAQ(xq1, 48);
        // scatter t4 slice into conv layout t4s[(g*16+p)*20 + l+2]
#pragma unroll
        for (int pp = 0; pp < 8; pp++) {
            t4s[(gS * 16 + p0 + pp) * LROW + lS + 2] = am[pp];
        }
    }
    __syncthreads();   // barrier 1: t4s/w2s/wcs ready

    // ================= conv phase (verified structure, unchanged) ==========
    const int p  = tid & 15;
    const int jh = tid >> 4;        // 0..15
    const int jb = jh * 2;          // channels j = jb, jb+1

    float acc[NH][2];
#pragma unroll
    for (int n = 0; n < NH; n++) { acc[n][0] = 0.f; acc[n][1] = 0.f; }

    for (int g = 0; g < NG; g++) {
        float row[LROW];
        const float* rp = &t4s[(g * 16 + p) * LROW];
#pragma unroll
        for (int q = 0; q < 5; q++) {
            float4 v = *reinterpret_cast<const float4*>(rp + q * 4);
            row[q * 4 + 0] = v.x; row[q * 4 + 1] = v.y;
            row[q * 4 + 2] = v.z; row[q * 4 + 3] = v.w;
        }
#pragma unroll
        for (int di = 0; di < 5; di++) {
            float2 w = *reinterpret_cast<const float2*>(&w2s[(g * 5 + di) * 32 + jb]);
#pragma unroll
            for (int n = 0; n < NH; n++) {
                float rv = row[n + di];
                acc[n][0] += rv * w.x;
                acc[n][1] += rv * w.y;
            }
        }
        float2 c0 = *reinterpret_cast<const float2*>(&wcs[g * 32 + jb]);
        float2 c1 = *reinterpret_cast<const float2*>(&wcs[256 + g * 32 + jb]);
        float r2 = row[2], r15 = row[15];
        acc[0][0]  -= r2  * c0.x; acc[0][1]  -= r2  * c0.y;
        acc[13][0] -= r15 * c1.x; acc[13][1] -= r15 * c1.y;
    }

    __syncthreads();   // barrier 2: conv reads done; reuse lds[0,3840) as stage

    // ---- output in two 256-channel rounds; verified mod-14 rotation,
    //      stride 15 (injective, slot 14 unused), float2 global stores ----
    int rotw = jh * 2;
    rotw -= (rotw >= 14) ? 14 : 0;
    rotw -= (rotw >= 14) ? 14 : 0;               // 2*jh <= 30: two wraps max

    const int k7 = tid & 7;
    const int cb = tid >> 3;                     // 0..31
    float* ob = out + (size_t)b * 512 * HH + (size_t)o * NH;

#pragma unroll
    for (int h = 0; h < 2; h++) {
        if ((jh >> 3) == h) {                    // owners of half h stage
#pragma unroll
            for (int jj = 0; jj < 2; jj++) {
                int cl = ((jb + jj) * 16 + p) & 255;   // local channel 0..255
                int sb = cl * 15;
#pragma unroll
                for (int n = 0; n < NH; n++) {
                    int rn = n + rotw;
                    rn -= (rn >= 14) ? 14 : 0;
                    lds[sb + rn] = acc[n][jj];
                }
            }
        }
        __syncthreads();                         // staged
        if (k7 < 7) {
#pragma unroll
            for (int r = 0; r < 8; r++) {        // 256 channels = 32 cb x 8 r
                int cl  = cb + 32 * r;
                int cg  = h * 256 + cl;          // c>>5 = h*8 + r
                int rot = (2 * (h * 8 + r)) % 14;   // compile-time per (h,r)
                int rn  = 2 * k7 + rot;          // even, <= 24
                rn -= (rn >= 14) ? 14 : 0;       // even, <= 12 -> rn+1 safe
                float v0 = lds[cl * 15 + rn];
                float v1 = lds[cl * 15 + rn + 1];
                *reinterpret_cast<float2*>(ob + (size_t)cg * HH + 2 * k7) =
                    make_float2(v0, v1);
            }
        }
        __syncthreads();                         // reads done before next stage
    }
}

extern "C" void kernel_launch(void* const* d_in, const int* in_sizes, int n_in,
                              void* d_out, int out_size, void* d_ws, size_t ws_size,
                              hipStream_t stream) {
    const float* x     = (const float*)d_in[0];
    const float* wconv = (const float*)d_in[1];
    const float* wmix  = (const float*)d_in[2];
    float* out = (float*)d_out;
    (void)d_ws; (void)ws_size;

    // one block per (b, o), XCD-swizzled decode inside the kernel
    fused_kernel<<<NB * NH, 256, 0, stream>>>(x, wconv, wmix, out);
}